// Round 19
// baseline (351.214 us; speedup 1.0000x reference)
//
#include <hip/hip_runtime.h>
#include <stdint.h>

typedef short bf16x8 __attribute__((ext_vector_type(8)));
typedef float f32x4 __attribute__((ext_vector_type(4)));

#define DEVINL static __device__ __forceinline__
#define SB() __builtin_amdgcn_sched_barrier(0)

DEVINL unsigned short f2bf(float f) {
    union { float f; uint32_t u; } v; v.f = f;
    return (unsigned short)((v.u + 0x7FFFu + ((v.u >> 16) & 1u)) >> 16);
}

DEVINL bf16x8 cvt8(f32x4 lo, f32x4 hi) {
    bf16x8 r;
    r[0] = (short)f2bf(lo[0]); r[1] = (short)f2bf(lo[1]);
    r[2] = (short)f2bf(lo[2]); r[3] = (short)f2bf(lo[3]);
    r[4] = (short)f2bf(hi[0]); r[5] = (short)f2bf(hi[1]);
    r[6] = (short)f2bf(hi[2]); r[7] = (short)f2bf(hi[3]);
    return r;
}

DEVINL void load_lds16(const void* g, void* l) {
    __builtin_amdgcn_global_load_lds(
        (const __attribute__((address_space(1))) void*)g,
        (__attribute__((address_space(3))) void*)l, 16, 0, 0);
}

// ---- weights-only convert: 4x 1024x1024 f32 -> bf16 ----
__global__ __launch_bounds__(256) void k_cvtW(
    const float* __restrict__ s0, const float* __restrict__ s1,
    const float* __restrict__ s2, const float* __restrict__ s3,
    unsigned short* __restrict__ d0, unsigned short* __restrict__ d1,
    unsigned short* __restrict__ d2, unsigned short* __restrict__ d3)
{
    const float* srcs[4] = {s0, s1, s2, s3};
    unsigned short* dsts[4] = {d0, d1, d2, d3};
    const int wsel = blockIdx.x >> 7;          // 4 x 128 blocks
    const int blk  = blockIdx.x & 127;
    const float* src = srcs[wsel];
    unsigned short* dst = dsts[wsel];
    for (int i = blk * 256 + threadIdx.x; i < 131072; i += 128 * 256) {
        const f32x4 f0 = reinterpret_cast<const f32x4*>(src)[2 * i];
        const f32x4 f1 = reinterpret_cast<const f32x4*>(src)[2 * i + 1];
        reinterpret_cast<bf16x8*>(dst)[i] = cvt8(f0, f1);
    }
}

#define MFMA_QUAD(mi, nj, av, bv)                                              \
    __builtin_amdgcn_s_setprio(1);                                             \
    _Pragma("unroll")                                                          \
    for (int i = 0; i < 4; ++i)                                                \
        _Pragma("unroll")                                                      \
        for (int j = 0; j < 2; ++j)                                            \
            _Pragma("unroll")                                                  \
            for (int ks = 0; ks < 2; ++ks)                                     \
                acc[(mi) * 4 + i][(nj) * 2 + j] =                              \
                    __builtin_amdgcn_mfma_f32_16x16x32_bf16(                   \
                        av[i][ks], bv[j][ks], acc[(mi)*4+i][(nj)*2+j], 0, 0, 0); \
    __builtin_amdgcn_s_setprio(0);

// shared epilogue: EPI 0 = f32+bias; 1 = LN*0.125 bf16; 2 = vperm bf16; 3 = LN bf16
template<int EPI>
DEVINL void epi_write(f32x4 (&acc)[8][4], void* Cout,
                      const float* bias, const float* gamma, const float* beta,
                      int m0, int n0, int wr, int wc, int lane, int wg)
{
    constexpr int N = 1024;
    const int rr = lane & 15;
    const int rg = lane >> 4;
    if constexpr (EPI == 0) {
        #pragma unroll
        for (int jj = 0; jj < 4; ++jj) {
            const int col = n0 + wc * 64 + jj * 16 + rr;
            const float bv = bias[col];
            #pragma unroll
            for (int i = 0; i < 8; ++i) {
                const int row0 = m0 + wr * 128 + i * 16 + rg * 4;
                #pragma unroll
                for (int r = 0; r < 4; ++r)
                    reinterpret_cast<float*>(Cout)[(size_t)(row0 + r) * N + col] =
                        acc[i][jj][r] + bv;
            }
        }
    } else if constexpr (EPI == 1 || EPI == 3) {
        const float scale = (EPI == 1) ? 0.125f : 1.0f;
        float gm[4], bt[4];
        #pragma unroll
        for (int jj = 0; jj < 4; ++jj) { gm[jj] = gamma[jj * 16 + rr]; bt[jj] = beta[jj * 16 + rr]; }
        #pragma unroll
        for (int i = 0; i < 8; ++i)
            #pragma unroll
            for (int r = 0; r < 4; ++r) {
                float s = 0.f, sq = 0.f;
                #pragma unroll
                for (int jj = 0; jj < 4; ++jj) {
                    const float v = acc[i][jj][r];
                    s += v; sq += v * v;
                }
                s  += __shfl_xor(s, 1);  s  += __shfl_xor(s, 2);
                s  += __shfl_xor(s, 4);  s  += __shfl_xor(s, 8);
                sq += __shfl_xor(sq, 1); sq += __shfl_xor(sq, 2);
                sq += __shfl_xor(sq, 4); sq += __shfl_xor(sq, 8);
                const float mu = s * 0.015625f;
                const float var = sq * 0.015625f - mu * mu;
                const float inv = rsqrtf(var + 1e-5f);
                const int row = m0 + wr * 128 + i * 16 + rg * 4 + r;
                #pragma unroll
                for (int jj = 0; jj < 4; ++jj) {
                    const int col = n0 + wc * 64 + jj * 16 + rr;
                    const float val = ((acc[i][jj][r] - mu) * inv * gm[jj] + bt[jj]) * scale;
                    reinterpret_cast<unsigned short*>(Cout)[(size_t)row * N + col] = f2bf(val);
                }
            }
    } else {  // EPI == 2: vperm[t][ (d>>4)*256 + (g>>3)*128 + (d&15)*8 + (g&7) ]
        const int g = (wg & 3) * 4 + wc;
        const int kqv = g >> 3;
        const int ev = g & 7;
        #pragma unroll
        for (int i = 0; i < 8; ++i)
            #pragma unroll
            for (int r = 0; r < 4; ++r) {
                const int t = m0 + wr * 128 + i * 16 + rg * 4 + r;
                #pragma unroll
                for (int jj = 0; jj < 4; ++jj)
                    reinterpret_cast<unsigned short*>(Cout)[
                        (size_t)t * 1024 + jj * 256 + kqv * 128 + rr * 8 + ev] =
                        f2bf(acc[i][jj][r]);
            }
    }
}

// ============ double-buffered 256^2 body; AF32: A read as f32, cvt in-kernel ============
// Staging per tile kt (for kt+1): ph0 A (8 reg-loads if AF32 else 4 gload_lds),
// ph1 B-nh0 (2 gload_lds), ph2 B-nh1 (2 gload_lds), ph3 vmcnt(4) [+ cvt + 4 ds_write]
// + barrier publishes A. b0/b1 read after their publishing barriers (ph0/ph1).
// vmcnt: ph0/ph1 = 10 (AF32) or 6; ph3 = 4; epilogue 2/0. Never 0 mid-loop.
#define LOFF(buf, ab, ks, row) (((((buf) * 2 + (ab)) * 2 + (ks)) * 256 + (row)) * 32)

template<int EPI, int AF32>
DEVINL void gemm256_body(
    const void* __restrict__ A,
    const unsigned short* __restrict__ B,
    void* __restrict__ Cout,
    const float* __restrict__ bias,
    const float* __restrict__ gamma,
    const float* __restrict__ beta,
    unsigned short* lds, int bid, int nwg, int tid)
{
    constexpr int K = 1024;
    constexpr int NT = 16;

    const int wg  = (bid & 7) * (nwg >> 3) + (bid >> 3);   // XCD swizzle (nwg%8==0)
    const int m0 = (wg >> 2) * 256;
    const int n0 = (wg & 3) * 256;

    const int w = tid >> 6;
    const int lane = tid & 63;
    const int wr = w >> 2;
    const int wc = w & 3;

    const int srow = lane >> 2;
    const int sseg = lane & 3;
    const int sslot = sseg ^ ((srow >> 1) & 3);

    const float* Af = (const float*)A;
    const unsigned short* Ab = (const unsigned short*)A;

    f32x4 acc[8][4] = {};
    f32x4 fA[8];

    // A staging (granules g = sel*2+j)
    auto stage_A_gl = [&](int buf, int kt) {      // AF32 == 0
        const int k0 = kt * 64;
        #pragma unroll
        for (int sel = 0; sel < 2; ++sel)
            #pragma unroll
            for (int j = 0; j < 2; ++j) {
                const int c = (w << 1) | j;
                const int ks = c >> 3;
                const int c3 = c & 7;
                const int rg = sel * 4 + (c3 & 3) + ((c3 >> 2) << 3);
                const int row = rg * 16 + srow;
                load_lds16(Ab + (size_t)(m0 + row) * K + k0 + ks * 32 + sslot * 8,
                           lds + LOFF(buf, 0, ks, rg * 16));
            }
    };
    auto issue_A = [&](int kt) {                  // AF32 == 1
        const int k0 = kt * 64;
        #pragma unroll
        for (int sel = 0; sel < 2; ++sel)
            #pragma unroll
            for (int j = 0; j < 2; ++j) {
                const int g = sel * 2 + j;
                const int c = (w << 1) | j;
                const int ks = c >> 3;
                const int c3 = c & 7;
                const int rg = sel * 4 + (c3 & 3) + ((c3 >> 2) << 3);
                const int row = rg * 16 + srow;
                const float* s = Af + (size_t)(m0 + row) * K + k0 + ks * 32 + sslot * 8;
                fA[2 * g]     = *reinterpret_cast<const f32x4*>(s);
                fA[2 * g + 1] = *reinterpret_cast<const f32x4*>(s + 4);
            }
    };
    auto write_A = [&](int buf) {                 // AF32 == 1
        #pragma unroll
        for (int sel = 0; sel < 2; ++sel)
            #pragma unroll
            for (int j = 0; j < 2; ++j) {
                const int g = sel * 2 + j;
                const int c = (w << 1) | j;
                const int ks = c >> 3;
                const int c3 = c & 7;
                const int rg = sel * 4 + (c3 & 3) + ((c3 >> 2) << 3);
                *reinterpret_cast<bf16x8*>(lds + LOFF(buf, 0, ks, rg * 16) + lane * 8) =
                    cvt8(fA[2 * g], fA[2 * g + 1]);
            }
    };
    // B staging: sel 0 = nh0 (u1), sel 1 = nh1 (u3)
    auto stage_B = [&](int buf, int kt, int sel) {
        const int k0 = kt * 64;
        #pragma unroll
        for (int j = 0; j < 2; ++j) {
            const int c = (w << 1) | j;
            const int ks = c >> 3;
            const int c3 = c & 7;
            const int rg = sel * 2 + (c3 & 1) + ((c3 >> 1) << 2);
            const int row = rg * 16 + srow;
            load_lds16(B + (size_t)(n0 + row) * K + k0 + ks * 32 + sslot * 8,
                       lds + LOFF(buf, 1, ks, rg * 16));
        }
    };

    const int rr = lane & 15;
    const int rdslot = ((lane >> 4) ^ ((rr >> 1) & 3)) * 8;

    auto rd_a = [&](bf16x8 (&dst)[4][2], int cur, int mh) {
        #pragma unroll
        for (int i = 0; i < 4; ++i)
            #pragma unroll
            for (int ks = 0; ks < 2; ++ks)
                dst[i][ks] = *reinterpret_cast<const bf16x8*>(
                    lds + LOFF(cur, 0, ks, wr * 128 + mh * 64 + i * 16 + rr) + rdslot);
    };
    auto rd_b = [&](bf16x8 (&dst)[2][2], int cur, int nh) {
        #pragma unroll
        for (int j = 0; j < 2; ++j)
            #pragma unroll
            for (int ks = 0; ks < 2; ++ks)
                dst[j][ks] = *reinterpret_cast<const bf16x8*>(
                    lds + LOFF(cur, 1, ks, wc * 64 + nh * 32 + j * 16 + rr) + rdslot);
    };

    // ---- prologue: stage tile 0, publish A[0] (u1,u3 stay in flight) ----
    if constexpr (AF32) issue_A(0); else stage_A_gl(0, 0);
    stage_B(0, 0, 0);
    stage_B(0, 0, 1);
    asm volatile("s_waitcnt vmcnt(4)" ::: "memory");   // retire A-stage of tile 0
    SB();
    if constexpr (AF32) { write_A(0); SB(); }
    asm volatile("s_waitcnt lgkmcnt(0)" ::: "memory");
    SB();
    __builtin_amdgcn_s_barrier();
    SB();

    bf16x8 a[4][2], b0[2][2], b1[2][2];
    int cur = 0;
    for (int kt = 0; kt < NT - 1; ++kt) {
        const int nxt = cur ^ 1;

        // ---- ph0: A[cur] mh0 reads; stage A[kt+1]; publish u1[kt]; b0 reads ----
        rd_a(a, cur, 0);
        SB();
        if constexpr (AF32) issue_A(kt + 1); else stage_A_gl(nxt, kt + 1);
        SB();
        if constexpr (AF32) { asm volatile("s_waitcnt vmcnt(10)" ::: "memory"); }
        else                { asm volatile("s_waitcnt vmcnt(6)" ::: "memory"); }
        __builtin_amdgcn_s_barrier();                  // publish u1[kt]
        SB();
        rd_b(b0, cur, 0);
        SB();
        asm volatile("s_waitcnt lgkmcnt(0)" ::: "memory");
        SB();
        MFMA_QUAD(0, 0, a, b0)

        // ---- ph1: stage u1[kt+1]; publish u3[kt]; b1 reads ----
        stage_B(nxt, kt + 1, 0);
        SB();
        if constexpr (AF32) { asm volatile("s_waitcnt vmcnt(10)" ::: "memory"); }
        else                { asm volatile("s_waitcnt vmcnt(6)" ::: "memory"); }
        __builtin_amdgcn_s_barrier();                  // publish u3[kt]
        SB();
        rd_b(b1, cur, 1);
        SB();
        asm volatile("s_waitcnt lgkmcnt(0)" ::: "memory");
        SB();
        MFMA_QUAD(0, 1, a, b1)

        // ---- ph2: A[cur] mh1 reads; stage u3[kt+1]; no barrier ----
        rd_a(a, cur, 1);
        SB();
        stage_B(nxt, kt + 1, 1);
        SB();
        asm volatile("s_waitcnt lgkmcnt(0)" ::: "memory");
        SB();
        MFMA_QUAD(1, 0, a, b0)

        // ---- ph3: retire A[kt+1] loads; cvt+write (AF32); publish A[kt+1] ----
        asm volatile("s_waitcnt vmcnt(4)" ::: "memory");
        SB();
        if constexpr (AF32) { write_A(nxt); SB(); }
        MFMA_QUAD(1, 1, a, b1)
        asm volatile("s_waitcnt lgkmcnt(0)" ::: "memory");
        SB();
        __builtin_amdgcn_s_barrier();                  // publish A[kt+1]
        SB();
        cur = nxt;
    }

    // ---- epilogue tile NT-1: no staging; outstanding {u1,u3} ----
    {
        rd_a(a, cur, 0);
        SB();
        asm volatile("s_waitcnt vmcnt(2)" ::: "memory");   // retire u1
        __builtin_amdgcn_s_barrier();
        SB();
        rd_b(b0, cur, 0);
        SB();
        asm volatile("s_waitcnt lgkmcnt(0)" ::: "memory");
        SB();
        MFMA_QUAD(0, 0, a, b0)

        asm volatile("s_waitcnt vmcnt(0)" ::: "memory");   // retire u3
        __builtin_amdgcn_s_barrier();
        SB();
        rd_b(b1, cur, 1);
        SB();
        asm volatile("s_waitcnt lgkmcnt(0)" ::: "memory");
        SB();
        MFMA_QUAD(0, 1, a, b1)

        rd_a(a, cur, 1);
        SB();
        asm volatile("s_waitcnt lgkmcnt(0)" ::: "memory");
        SB();
        MFMA_QUAD(1, 0, a, b0)
        MFMA_QUAD(1, 1, a, b1)
    }

    epi_write<EPI>(acc, Cout, bias, gamma, beta, m0, n0, wr, wc, lane, wg);
}

#undef MFMA_QUAD

template<int EPI, int AF32>
__global__ __launch_bounds__(512, 2) void k_gemm256(
    const void* __restrict__ A,
    const unsigned short* __restrict__ B,
    void* __restrict__ Cout,
    const float* __restrict__ bias,
    const float* __restrict__ gamma,
    const float* __restrict__ beta)
{
    __shared__ __align__(16) unsigned short lds[2 * 2 * 2 * 256 * 32];
    gemm256_body<EPI, AF32>(A, B, Cout, bias, gamma, beta, lds, blockIdx.x, gridDim.x, threadIdx.x);
}

// ---- k-proj (EPI=3) and v-proj (EPI=2), both f32-A, side by side ----
__global__ __launch_bounds__(512, 2) void k_gemm256kv(
    const float* __restrict__ Ak,
    const unsigned short* __restrict__ Bk,
    void* __restrict__ Ck,
    const float* __restrict__ Av,
    const unsigned short* __restrict__ Bv,
    void* __restrict__ Cv,
    const float* __restrict__ gamma,
    const float* __restrict__ beta)
{
    __shared__ __align__(16) unsigned short lds[2 * 2 * 2 * 256 * 32];
    if (blockIdx.x < 128)
        gemm256_body<3, 1>(Ak, Bk, Ck, nullptr, gamma, beta, lds, blockIdx.x, 128, threadIdx.x);
    else
        gemm256_body<2, 1>(Av, Bv, Cv, nullptr, nullptr, nullptr, lds, blockIdx.x - 128, 128, threadIdx.x);
}

// ---------------- per-token HxH attention, one wave per token, MFMA ----------------
__global__ __launch_bounds__(256) void k_attn2(
    const unsigned short* __restrict__ qln,
    const unsigned short* __restrict__ kln,
    const unsigned short* __restrict__ vperm,
    unsigned short* __restrict__ xout)
{
    __shared__ unsigned short ps[4][256];
    __shared__ unsigned short xs[4][16 * 68];

    const int w = threadIdx.x >> 6;
    const int lane = threadIdx.x & 63;
    const int token = blockIdx.x * 4 + w;
    const int b = token >> 11;
    const int n = token & 2047;
    const int tokk = (b & 3) * 2048 + n;
    const int rr = lane & 15;
    const int kq = lane >> 4;

    const unsigned short* qp = qln + (size_t)token * 1024 + rr * 64 + kq * 8;
    const unsigned short* kp = kln + (size_t)tokk * 1024 + rr * 64 + kq * 8;
    const bf16x8 aq0 = *reinterpret_cast<const bf16x8*>(qp);
    const bf16x8 aq1 = *reinterpret_cast<const bf16x8*>(qp + 32);
    const bf16x8 bk0 = *reinterpret_cast<const bf16x8*>(kp);
    const bf16x8 bk1 = *reinterpret_cast<const bf16x8*>(kp + 32);
    f32x4 s = {};
    s = __builtin_amdgcn_mfma_f32_16x16x32_bf16(aq0, bk0, s, 0, 0, 0);
    s = __builtin_amdgcn_mfma_f32_16x16x32_bf16(aq1, bk1, s, 0, 0, 0);

    #pragma unroll
    for (int r = 0; r < 4; ++r) {
        float m = s[r];
        m = fmaxf(m, __shfl_xor(m, 1));
        m = fmaxf(m, __shfl_xor(m, 2));
        m = fmaxf(m, __shfl_xor(m, 4));
        m = fmaxf(m, __shfl_xor(m, 8));
        const float e = __expf(s[r] - m);
        float t = e;
        t += __shfl_xor(t, 1); t += __shfl_xor(t, 2);
        t += __shfl_xor(t, 4); t += __shfl_xor(t, 8);
        ps[w][(kq * 4 + r) * 16 + rr] = f2bf(e / t);
    }

    bf16x8 ap = {};
    if (kq < 2)
        ap = *reinterpret_cast<const bf16x8*>(&ps[w][rr * 16 + kq * 8]);

    const unsigned short* vp = vperm + (size_t)tokk * 1024;
    #pragma unroll
    for (int dblk = 0; dblk < 4; ++dblk) {
        bf16x8 bv = {};
        if (kq < 2)
            bv = *reinterpret_cast<const bf16x8*>(vp + dblk * 256 + kq * 128 + rr * 8);
        f32x4 z = {};
        const f32x4 x = __builtin_amdgcn_mfma_f32_16x16x32_bf16(ap, bv, z, 0, 0, 0);
        #pragma unroll
        for (int r = 0; r < 4; ++r)
            xs[w][(kq * 4 + r) * 68 + dblk * 16 + rr] = f2bf(x[r]);
    }

    const int h2 = lane >> 2;
    const int sg = lane & 3;
    const uint4 lo = *reinterpret_cast<const uint4*>(&xs[w][h2 * 68 + sg * 16]);
    const uint4 hi = *reinterpret_cast<const uint4*>(&xs[w][h2 * 68 + sg * 16 + 8]);
    unsigned short* dst = xout + (size_t)b * 2048 * 1024 +
                          (size_t)(h2 * 128 + (n >> 4)) * 1024 + (n & 15) * 64 + sg * 16;
    *reinterpret_cast<uint4*>(dst) = lo;
    *reinterpret_cast<uint4*>(dst + 8) = hi;
}

extern "C" void kernel_launch(void* const* d_in, const int* in_sizes, int n_in,
                              void* d_out, int out_size, void* d_ws, size_t ws_size,
                              hipStream_t stream) {
    const float* q     = (const float*)d_in[0];
    const float* k     = (const float*)d_in[1];
    const float* v     = (const float*)d_in[2];
    const float* Wq    = (const float*)d_in[3];
    const float* Wk    = (const float*)d_in[4];
    const float* Wv    = (const float*)d_in[5];
    const float* Wo    = (const float*)d_in[6];
    const float* bo    = (const float*)d_in[7];
    const float* gamma = (const float*)d_in[8];
    const float* beta  = (const float*)d_in[9];
    float* out = (float*)d_out;

    char* ws = (char*)d_ws;
    const size_t MB = 1024 * 1024;
    unsigned short* xsc   = (unsigned short*)(ws + 0);        // 64 MiB
    unsigned short* qpb   = (unsigned short*)(ws + 64 * MB);  // 64 MiB
    unsigned short* klnb  = (unsigned short*)(ws + 128 * MB); // 16 MiB
    unsigned short* vpm   = (unsigned short*)(ws + 144 * MB); // 16 MiB
    unsigned short* Wkb   = (unsigned short*)(ws + 160 * MB);
    unsigned short* Wvb   = (unsigned short*)(ws + 162 * MB);
    unsigned short* Wqb   = (unsigned short*)(ws + 164 * MB);
    unsigned short* Wob   = (unsigned short*)(ws + 166 * MB);

    // 1) weights-only convert
    k_cvtW<<<512, 256, 0, stream>>>(Wk, Wv, Wq, Wo, Wkb, Wvb, Wqb, Wob);

    // 2) k-proj (+LN) and v-proj (+vperm), f32 A fused convert, full GPU
    k_gemm256kv<<<256, 512, 0, stream>>>(k, Wkb, klnb, v, Wvb, vpm, gamma, beta);

    // 3) q-proj + fused LN*0.125, f32 A fused convert
    k_gemm256<1, 1><<<512, 512, 0, stream>>>(q, Wqb, qpb, nullptr, gamma, beta);

    // 4) attention (MFMA, coalesced scrambled store)
    k_attn2<<<8192, 256, 0, stream>>>(qpb, klnb, vpm, xsc);

    // 5) out-proj, bf16 A (attn output), f32 + bias into d_out
    k_gemm256<0, 0><<<512, 512, 0, stream>>>(xsc, Wob, out, bo, nullptr, nullptr);
}

// Round 20
// 299.229 us; speedup vs baseline: 1.1737x; 1.1737x over previous
//
#include <hip/hip_runtime.h>
#include <stdint.h>

typedef short bf16x8 __attribute__((ext_vector_type(8)));
typedef float f32x4 __attribute__((ext_vector_type(4)));

#define DEVINL static __device__ __forceinline__
#define SB() __builtin_amdgcn_sched_barrier(0)

DEVINL unsigned short f2bf(float f) {
    union { float f; uint32_t u; } v; v.f = f;
    return (unsigned short)((v.u + 0x7FFFu + ((v.u >> 16) & 1u)) >> 16);
}
DEVINL float bf2f(unsigned short b) {
    union { uint32_t u; float f; } v; v.u = ((uint32_t)b) << 16;
    return v.f;
}

DEVINL void load_lds16(const void* g, void* l) {
    __builtin_amdgcn_global_load_lds(
        (const __attribute__((address_space(1))) void*)g,
        (__attribute__((address_space(3))) void*)l, 16, 0, 0);
}

// ---- one launch converting q, k, v and the 4 weights ----
// per thread/iter: 2 consecutive float4 loads -> one 16B bf16x8 store
__global__ __launch_bounds__(256) void k_cvtall(
    const float* __restrict__ q, const float* __restrict__ k, const float* __restrict__ v,
    const float* __restrict__ w0, const float* __restrict__ w1,
    const float* __restrict__ w2, const float* __restrict__ w3,
    unsigned short* __restrict__ dq, unsigned short* __restrict__ dk,
    unsigned short* __restrict__ dv,
    unsigned short* __restrict__ dw0, unsigned short* __restrict__ dw1,
    unsigned short* __restrict__ dw2, unsigned short* __restrict__ dw3)
{
    const float* src; unsigned short* dst; int n8, blk, nblk;
    const int b = blockIdx.x;
    if (b < 2048)      { src = q; dst = dq; n8 = 4194304; blk = b;        nblk = 2048; }
    else if (b < 2560) { src = k; dst = dk; n8 = 1048576; blk = b - 2048; nblk = 512; }
    else if (b < 3072) { src = v; dst = dv; n8 = 1048576; blk = b - 2560; nblk = 512; }
    else {
        const int wsel = (b - 3072) >> 6;
        const float* ws_[4] = {w0, w1, w2, w3};
        unsigned short* wd_[4] = {dw0, dw1, dw2, dw3};
        src = ws_[wsel]; dst = wd_[wsel]; n8 = 131072; blk = (b - 3072) & 63; nblk = 64;
    }
    const int stride = nblk * 256;
    for (int i = blk * 256 + threadIdx.x; i < n8; i += stride) {
        const float4 f0 = reinterpret_cast<const float4*>(src)[2 * i];
        const float4 f1 = reinterpret_cast<const float4*>(src)[2 * i + 1];
        bf16x8 o;
        o[0] = (short)f2bf(f0.x); o[1] = (short)f2bf(f0.y);
        o[2] = (short)f2bf(f0.z); o[3] = (short)f2bf(f0.w);
        o[4] = (short)f2bf(f1.x); o[5] = (short)f2bf(f1.y);
        o[6] = (short)f2bf(f1.z); o[7] = (short)f2bf(f1.w);
        reinterpret_cast<bf16x8*>(dst)[i] = o;
    }
}

#define MFMA_QUAD(mi, nj, av, bv)                                              \
    __builtin_amdgcn_s_setprio(1);                                             \
    _Pragma("unroll")                                                          \
    for (int i = 0; i < 4; ++i)                                                \
        _Pragma("unroll")                                                      \
        for (int j = 0; j < 2; ++j)                                            \
            _Pragma("unroll")                                                  \
            for (int ks = 0; ks < 2; ++ks)                                     \
                acc[(mi) * 4 + i][(nj) * 2 + j] =                              \
                    __builtin_amdgcn_mfma_f32_16x16x32_bf16(                   \
                        av[i][ks], bv[j][ks], acc[(mi)*4+i][(nj)*2+j], 0, 0, 0); \
    __builtin_amdgcn_s_setprio(0);

// shared epilogue: EPI 0 = f32+bias; 1 = LN*0.125 bf16; 2 = vperm bf16; 3 = LN bf16
template<int EPI>
DEVINL void epi_write(f32x4 (&acc)[8][4], void* Cout,
                      const float* bias, const float* gamma, const float* beta,
                      int m0, int n0, int wr, int wc, int lane, int wg)
{
    constexpr int N = 1024;
    const int rr = lane & 15;
    const int rg = lane >> 4;
    if constexpr (EPI == 0) {
        #pragma unroll
        for (int jj = 0; jj < 4; ++jj) {
            const int col = n0 + wc * 64 + jj * 16 + rr;
            const float bv = bias[col];
            #pragma unroll
            for (int i = 0; i < 8; ++i) {
                const int row0 = m0 + wr * 128 + i * 16 + rg * 4;
                #pragma unroll
                for (int r = 0; r < 4; ++r)
                    reinterpret_cast<float*>(Cout)[(size_t)(row0 + r) * N + col] =
                        acc[i][jj][r] + bv;
            }
        }
    } else if constexpr (EPI == 1 || EPI == 3) {
        const float scale = (EPI == 1) ? 0.125f : 1.0f;
        float gm[4], bt[4];
        #pragma unroll
        for (int jj = 0; jj < 4; ++jj) { gm[jj] = gamma[jj * 16 + rr]; bt[jj] = beta[jj * 16 + rr]; }
        #pragma unroll
        for (int i = 0; i < 8; ++i)
            #pragma unroll
            for (int r = 0; r < 4; ++r) {
                float s = 0.f, sq = 0.f;
                #pragma unroll
                for (int jj = 0; jj < 4; ++jj) {
                    const float v = acc[i][jj][r];
                    s += v; sq += v * v;
                }
                s  += __shfl_xor(s, 1);  s  += __shfl_xor(s, 2);
                s  += __shfl_xor(s, 4);  s  += __shfl_xor(s, 8);
                sq += __shfl_xor(sq, 1); sq += __shfl_xor(sq, 2);
                sq += __shfl_xor(sq, 4); sq += __shfl_xor(sq, 8);
                const float mu = s * 0.015625f;
                const float var = sq * 0.015625f - mu * mu;
                const float inv = rsqrtf(var + 1e-5f);
                const int row = m0 + wr * 128 + i * 16 + rg * 4 + r;
                #pragma unroll
                for (int jj = 0; jj < 4; ++jj) {
                    const int col = n0 + wc * 64 + jj * 16 + rr;
                    const float val = ((acc[i][jj][r] - mu) * inv * gm[jj] + bt[jj]) * scale;
                    reinterpret_cast<unsigned short*>(Cout)[(size_t)row * N + col] = f2bf(val);
                }
            }
    } else {  // EPI == 2: vperm[t][ (d>>4)*256 + (g>>3)*128 + (d&15)*8 + (g&7) ]
        const int g = (wg & 3) * 4 + wc;
        const int kqv = g >> 3;
        const int ev = g & 7;
        #pragma unroll
        for (int i = 0; i < 8; ++i)
            #pragma unroll
            for (int r = 0; r < 4; ++r) {
                const int t = m0 + wr * 128 + i * 16 + rg * 4 + r;
                #pragma unroll
                for (int jj = 0; jj < 4; ++jj)
                    reinterpret_cast<unsigned short*>(Cout)[
                        (size_t)t * 1024 + jj * 256 + kqv * 128 + rr * 8 + ev] =
                        f2bf(acc[i][jj][r]);
            }
    }
}

// ============ double-buffered body (r14, reads-before-barrier) ============
#define LOFF(buf, ab, ks, row) (((((buf) * 2 + (ab)) * 2 + (ks)) * 256 + (row)) * 32)

template<int EPI>
DEVINL void gemm256_body(
    const unsigned short* __restrict__ A,
    const unsigned short* __restrict__ B,
    void* __restrict__ Cout,
    const float* __restrict__ bias,
    const float* __restrict__ gamma,
    const float* __restrict__ beta,
    unsigned short* lds, int bid, int nwg, int tid)
{
    constexpr int K = 1024;
    constexpr int NT = 16;

    const int wg  = (bid & 7) * (nwg >> 3) + (bid >> 3);   // XCD swizzle (nwg%8==0)
    const int m0 = (wg >> 2) * 256;
    const int n0 = (wg & 3) * 256;

    const int w = tid >> 6;
    const int lane = tid & 63;
    const int wr = w >> 2;
    const int wc = w & 3;

    const int srow = lane >> 2;
    const int sseg = lane & 3;
    const int sslot = sseg ^ ((srow >> 1) & 3);

    f32x4 acc[8][4] = {};

    auto stage_unit = [&](int buf, int kt, int unit) {
        const int k0 = kt * 64;
        const int ab = unit & 1;
        const int sel = unit >> 1;
        #pragma unroll
        for (int j = 0; j < 2; ++j) {
            const int c  = (w << 1) | j;
            const int ks = c >> 3;
            const int c3 = c & 7;
            const int rg = ab ? (sel * 2 + (c3 & 1) + ((c3 >> 1) << 2))
                              : (sel * 4 + (c3 & 3) + ((c3 >> 2) << 3));
            const int row = rg * 16 + srow;
            const unsigned short* src =
                (ab ? B + (size_t)(n0 + row) * K : A + (size_t)(m0 + row) * K)
                + k0 + ks * 32 + sslot * 8;
            load_lds16(src, lds + LOFF(buf, ab, ks, rg * 16));
        }
    };

    const int rr = lane & 15;
    const int rdslot = ((lane >> 4) ^ ((rr >> 1) & 3)) * 8;

    auto rd_a = [&](bf16x8 (&dst)[4][2], int cur, int mh) {
        #pragma unroll
        for (int i = 0; i < 4; ++i)
            #pragma unroll
            for (int ks = 0; ks < 2; ++ks)
                dst[i][ks] = *reinterpret_cast<const bf16x8*>(
                    lds + LOFF(cur, 0, ks, wr * 128 + mh * 64 + i * 16 + rr) + rdslot);
    };
    auto rd_b = [&](bf16x8 (&dst)[2][2], int cur, int nh) {
        #pragma unroll
        for (int j = 0; j < 2; ++j)
            #pragma unroll
            for (int ks = 0; ks < 2; ++ks)
                dst[j][ks] = *reinterpret_cast<const bf16x8*>(
                    lds + LOFF(cur, 1, ks, wc * 64 + nh * 32 + j * 16 + rr) + rdslot);
    };

    // prologue: tile 0 units in order u0,u1,u3,u2; publish u0,u1
    stage_unit(0, 0, 0);
    stage_unit(0, 0, 1);
    stage_unit(0, 0, 3);
    stage_unit(0, 0, 2);
    asm volatile("s_waitcnt vmcnt(4)" ::: "memory");
    __builtin_amdgcn_s_barrier();
    SB();

    bf16x8 a[4][2], b0[2][2], b1[2][2];
    int cur = 0;
    for (int kt = 0; kt < NT - 1; ++kt) {
        const int nxt = cur ^ 1;

        // ph0: reads u0,u1[kt] (published @ prev ph3)
        rd_a(a, cur, 0);
        rd_b(b0, cur, 0);
        SB();
        stage_unit(nxt, kt + 1, 0);
        asm volatile("s_waitcnt vmcnt(4)" ::: "memory");   // retire u3[kt]
        __builtin_amdgcn_s_barrier();                      // publish u3[kt]
        SB();
        asm volatile("s_waitcnt lgkmcnt(0)" ::: "memory");
        SB();
        MFMA_QUAD(0, 0, a, b0)

        // ph1: reads u3[kt]
        rd_b(b1, cur, 1);
        SB();
        stage_unit(nxt, kt + 1, 1);
        asm volatile("s_waitcnt vmcnt(4)" ::: "memory");   // retire u2[kt]
        __builtin_amdgcn_s_barrier();                      // publish u2[kt]
        SB();
        asm volatile("s_waitcnt lgkmcnt(0)" ::: "memory");
        SB();
        MFMA_QUAD(0, 1, a, b1)

        // ph2: reads u2[kt]
        rd_a(a, cur, 1);
        SB();
        stage_unit(nxt, kt + 1, 3);
        __builtin_amdgcn_s_barrier();
        SB();
        asm volatile("s_waitcnt lgkmcnt(0)" ::: "memory");
        SB();
        MFMA_QUAD(1, 0, a, b0)

        // ph3: regs only; publish u0,u1[kt+1]
        stage_unit(nxt, kt + 1, 2);
        asm volatile("s_waitcnt vmcnt(4)" ::: "memory");   // retire u0,u1[kt+1]
        __builtin_amdgcn_s_barrier();
        SB();
        MFMA_QUAD(1, 1, a, b1)
        cur = nxt;
    }

    // epilogue tile NT-1: no prefetch; outstanding = {u3,u2}
    {
        rd_a(a, cur, 0);
        rd_b(b0, cur, 0);
        SB();
        asm volatile("s_waitcnt vmcnt(2)" ::: "memory");   // retire u3
        __builtin_amdgcn_s_barrier();
        SB();
        asm volatile("s_waitcnt lgkmcnt(0)" ::: "memory");
        SB();
        MFMA_QUAD(0, 0, a, b0)

        rd_b(b1, cur, 1);
        SB();
        asm volatile("s_waitcnt vmcnt(0)" ::: "memory");   // retire u2
        __builtin_amdgcn_s_barrier();
        SB();
        asm volatile("s_waitcnt lgkmcnt(0)" ::: "memory");
        SB();
        MFMA_QUAD(0, 1, a, b1)

        rd_a(a, cur, 1);
        SB();
        asm volatile("s_waitcnt lgkmcnt(0)" ::: "memory");
        SB();
        MFMA_QUAD(1, 0, a, b0)
        MFMA_QUAD(1, 1, a, b1)
    }

    epi_write<EPI>(acc, Cout, bias, gamma, beta, m0, n0, wr, wc, lane, wg);
}

#undef MFMA_QUAD

template<int EPI>
__global__ __launch_bounds__(512, 2) void k_gemm256(
    const unsigned short* __restrict__ A,
    const unsigned short* __restrict__ B,
    void* __restrict__ Cout,
    const float* __restrict__ bias,
    const float* __restrict__ gamma,
    const float* __restrict__ beta)
{
    __shared__ __align__(16) unsigned short lds[2 * 2 * 2 * 256 * 32];
    gemm256_body<EPI>(A, B, Cout, bias, gamma, beta, lds, blockIdx.x, gridDim.x, threadIdx.x);
}

// ---- k-proj (EPI=3, blocks 0-127) and v-proj (EPI=2, blocks 128-255) side by side ----
__global__ __launch_bounds__(512, 2) void k_gemm256kv(
    const unsigned short* __restrict__ Ak,
    const unsigned short* __restrict__ Bk,
    void* __restrict__ Ck,
    const unsigned short* __restrict__ Av,
    const unsigned short* __restrict__ Bv,
    void* __restrict__ Cv,
    const float* __restrict__ gamma,
    const float* __restrict__ beta)
{
    __shared__ __align__(16) unsigned short lds[2 * 2 * 2 * 256 * 32];
    if (blockIdx.x < 128)
        gemm256_body<3>(Ak, Bk, Ck, nullptr, gamma, beta, lds, blockIdx.x, 128, threadIdx.x);
    else
        gemm256_body<2>(Av, Bv, Cv, nullptr, nullptr, nullptr, lds, blockIdx.x - 128, 128, threadIdx.x);
}

// ---------------- per-token HxH attention, one wave per token, MFMA ----------------
// Output bounced through wave-private LDS tile -> coalesced 16B scrambled stores.
__global__ __launch_bounds__(256) void k_attn2(
    const unsigned short* __restrict__ qln,
    const unsigned short* __restrict__ kln,
    const unsigned short* __restrict__ vperm,
    unsigned short* __restrict__ xout)
{
    __shared__ unsigned short ps[4][256];     // P scratch
    __shared__ unsigned short xs[4][16 * 68]; // x transpose tile, stride 68 (bank-spread)

    const int w = threadIdx.x >> 6;
    const int lane = threadIdx.x & 63;
    const int token = blockIdx.x * 4 + w;
    const int b = token >> 11;
    const int n = token & 2047;
    const int tokk = (b & 3) * 2048 + n;
    const int rr = lane & 15;
    const int kq = lane >> 4;

    const unsigned short* qp = qln + (size_t)token * 1024 + rr * 64 + kq * 8;
    const unsigned short* kp = kln + (size_t)tokk * 1024 + rr * 64 + kq * 8;
    const bf16x8 aq0 = *reinterpret_cast<const bf16x8*>(qp);
    const bf16x8 aq1 = *reinterpret_cast<const bf16x8*>(qp + 32);
    const bf16x8 bk0 = *reinterpret_cast<const bf16x8*>(kp);
    const bf16x8 bk1 = *reinterpret_cast<const bf16x8*>(kp + 32);
    f32x4 s = {};
    s = __builtin_amdgcn_mfma_f32_16x16x32_bf16(aq0, bk0, s, 0, 0, 0);
    s = __builtin_amdgcn_mfma_f32_16x16x32_bf16(aq1, bk1, s, 0, 0, 0);

    #pragma unroll
    for (int r = 0; r < 4; ++r) {
        float m = s[r];
        m = fmaxf(m, __shfl_xor(m, 1));
        m = fmaxf(m, __shfl_xor(m, 2));
        m = fmaxf(m, __shfl_xor(m, 4));
        m = fmaxf(m, __shfl_xor(m, 8));
        const float e = __expf(s[r] - m);
        float t = e;
        t += __shfl_xor(t, 1); t += __shfl_xor(t, 2);
        t += __shfl_xor(t, 4); t += __shfl_xor(t, 8);
        ps[w][(kq * 4 + r) * 16 + rr] = f2bf(e / t);
    }

    bf16x8 ap = {};
    if (kq < 2)
        ap = *reinterpret_cast<const bf16x8*>(&ps[w][rr * 16 + kq * 8]);

    const unsigned short* vp = vperm + (size_t)tokk * 1024;
    #pragma unroll
    for (int dblk = 0; dblk < 4; ++dblk) {
        bf16x8 bv = {};
        if (kq < 2)
            bv = *reinterpret_cast<const bf16x8*>(vp + dblk * 256 + kq * 128 + rr * 8);
        f32x4 z = {};
        const f32x4 x = __builtin_amdgcn_mfma_f32_16x16x32_bf16(ap, bv, z, 0, 0, 0);
        #pragma unroll
        for (int r = 0; r < 4; ++r)
            xs[w][(kq * 4 + r) * 68 + dblk * 16 + rr] = f2bf(x[r]);
    }

    const int h2 = lane >> 2;
    const int sg = lane & 3;
    const uint4 lo = *reinterpret_cast<const uint4*>(&xs[w][h2 * 68 + sg * 16]);
    const uint4 hi = *reinterpret_cast<const uint4*>(&xs[w][h2 * 68 + sg * 16 + 8]);
    unsigned short* dst = xout + (size_t)b * 2048 * 1024 +
                          (size_t)(h2 * 128 + (n >> 4)) * 1024 + (n & 15) * 64 + sg * 16;
    *reinterpret_cast<uint4*>(dst) = lo;
    *reinterpret_cast<uint4*>(dst + 8) = hi;
}

extern "C" void kernel_launch(void* const* d_in, const int* in_sizes, int n_in,
                              void* d_out, int out_size, void* d_ws, size_t ws_size,
                              hipStream_t stream) {
    const float* q     = (const float*)d_in[0];
    const float* k     = (const float*)d_in[1];
    const float* v     = (const float*)d_in[2];
    const float* Wq    = (const float*)d_in[3];
    const float* Wk    = (const float*)d_in[4];
    const float* Wv    = (const float*)d_in[5];
    const float* Wo    = (const float*)d_in[6];
    const float* bo    = (const float*)d_in[7];
    const float* gamma = (const float*)d_in[8];
    const float* beta  = (const float*)d_in[9];
    float* out = (float*)d_out;

    char* ws = (char*)d_ws;
    const size_t MB = 1024 * 1024;
    unsigned short* qb    = (unsigned short*)(ws + 0);
    unsigned short* xsc   = (unsigned short*)(ws + 0);
    unsigned short* qpb   = (unsigned short*)(ws + 64 * MB);
    unsigned short* klnb  = (unsigned short*)(ws + 128 * MB);
    unsigned short* vbb   = (unsigned short*)(ws + 144 * MB);
    unsigned short* vpm   = (unsigned short*)(ws + 160 * MB);
    unsigned short* kbb   = (unsigned short*)(ws + 176 * MB);
    unsigned short* Wkb   = (unsigned short*)(ws + 192 * MB);
    unsigned short* Wvb   = (unsigned short*)(ws + 194 * MB);
    unsigned short* Wqb   = (unsigned short*)(ws + 196 * MB);
    unsigned short* Wob   = (unsigned short*)(ws + 198 * MB);

    // 1) one convert kernel: q, k, v, 4 weights (2xfloat4 -> bf16x8 stores)
    k_cvtall<<<3328, 256, 0, stream>>>(q, k, v, Wk, Wv, Wq, Wo,
                                       qb, kbb, vbb, Wkb, Wvb, Wqb, Wob);

    // 2) k-proj (+LN) and v-proj (+vperm) side by side, full GPU
    k_gemm256kv<<<256, 512, 0, stream>>>(kbb, Wkb, klnb, vbb, Wvb, vpm, gamma, beta);

    // 3) q-proj + fused LN*0.125 -> bf16 (double-buffered r14 schedule)
    k_gemm256<1><<<512, 512, 0, stream>>>(qb, Wqb, qpb, nullptr, gamma, beta);

    // 4) attention (MFMA, coalesced scrambled store) over qb region
    k_attn2<<<8192, 256, 0, stream>>>(qpb, klnb, vpm, xsc);

    // 5) out-proj, f32 + bias into d_out (double-buffered r14 schedule)
    k_gemm256<0><<<512, 512, 0, stream>>>(xsc, Wob, out, bo, nullptr, nullptr);
}